// Round 3
// baseline (1601.556 us; speedup 1.0000x reference)
//
#include <hip/hip_runtime.h>
#include <math.h>

typedef unsigned short u16;
typedef __attribute__((ext_vector_type(8))) short short8;
typedef __attribute__((ext_vector_type(4))) float f32x4;
typedef __attribute__((ext_vector_type(4))) unsigned short u16x4;

#define DEV static __device__ __forceinline__

DEV float b2f(u16 u) { unsigned v = ((unsigned)u) << 16; float f; __builtin_memcpy(&f, &v, 4); return f; }
DEV u16 f2b(float f) {
  unsigned u; __builtin_memcpy(&u, &f, 4);
  u += 0x7fffu + ((u >> 16) & 1u);
  return (u16)(u >> 16);
}

DEV float wred(float v) {
#pragma unroll
  for (int m = 1; m < 64; m <<= 1) v += __shfl_xor(v, m, 64);
  return v;
}

// Direct addrspace casts: clang emits addrspacecast (generic->as1 / generic->as3),
// which correctly extracts the LDS offset from a flat LDS pointer.
DEV void gld_lds16(const u16* src, u16* lds_dst) {
  __builtin_amdgcn_global_load_lds(
      (const __attribute__((address_space(1))) void*)src,
      (__attribute__((address_space(3))) void*)lds_dst, 16, 0, 0);
}

// C = A[M,K] @ W[N,K]^T (+bias/res/act). A,W bf16 bits (u16), acc fp32.
// EPI 0: GLU (virtual B = [Wz rows bn*64.. ; Wg rows 1024+bn*64..]) -> bf16 outB[M,1024]
// EPI 1: +res(+bias) -> bf16 outB[M,1024] at coloff
// EPI 2: +res(+bias) -> f32 outF[M,512]
// EPI 3: gelu(acc+bias) -> bf16 outB[M,2048]
// EPI 4: (acc+bias+res)*km -> f32 outF[M,512]
template <int EPI>
__global__ __launch_bounds__(256, 2) void gemm_tn(
    const u16* __restrict__ A, const u16* __restrict__ W, const int K,
    const float* __restrict__ bias, const float* __restrict__ res,
    const float* __restrict__ kmask, float* __restrict__ outF,
    u16* __restrict__ outB, const int coloff) {
  __shared__ u16 Ash[2][128 * 64];
  __shared__ u16 Bsh[2][128 * 64];
  const int tid = threadIdx.x;
  const int wid = tid >> 6;
  const int lane = tid & 63;
  const int bn = blockIdx.x;
  const int m0 = blockIdx.y << 7;

  f32x4 acc[2][8];
#pragma unroll
  for (int a = 0; a < 2; ++a)
#pragma unroll
    for (int b = 0; b < 8; ++b) acc[a][b] = f32x4{0.f, 0.f, 0.f, 0.f};

  // stage one 128x64 A-tile and B-tile. LDS dest linear (global_load_lds rule),
  // global source pre-swizzled chunk c -> c ^ (row&7) (involution; read applies same XOR).
  auto stage = [&](int buf, int k0) {
#pragma unroll
    for (int c = 0; c < 4; ++c) {
      const int j = wid * 256 + c * 64 + lane;
      const int row = j >> 3, cc = j & 7;
      const int scc = cc ^ (row & 7);
      const u16* src = A + (size_t)(m0 + row) * K + k0 + scc * 8;
      gld_lds16(src, &Ash[buf][(wid * 256 + c * 64) * 8]);
    }
#pragma unroll
    for (int c = 0; c < 4; ++c) {
      const int j = wid * 256 + c * 64 + lane;
      const int row = j >> 3, cc = j & 7;
      const int scc = cc ^ (row & 7);
      int wrow;
      if constexpr (EPI == 0)
        wrow = (row < 64) ? (bn * 64 + row) : (1024 + bn * 64 + (row - 64));
      else
        wrow = bn * 128 + row;
      const u16* src = W + (size_t)wrow * K + k0 + scc * 8;
      gld_lds16(src, &Bsh[buf][(wid * 256 + c * 64) * 8]);
    }
  };

  stage(0, 0);
  const int KT = K >> 6;
  for (int kt = 0; kt < KT; ++kt) {
    const int cur = kt & 1;
    __syncthreads();  // drains vmcnt (staging of buf cur) + lgkm (prev reads)
    if (kt + 1 < KT) stage(cur ^ 1, (kt + 1) << 6);
    const char* Ab = (const char*)(&Ash[cur][0]);
    const char* Bb = (const char*)(&Bsh[cur][0]);
#pragma unroll
    for (int kk = 0; kk < 2; ++kk) {
      const int cbb = kk * 64 + ((lane >> 4) << 4);
      short8 af[2];
#pragma unroll
      for (int mf = 0; mf < 2; ++mf) {
        const int row = wid * 32 + mf * 16 + (lane & 15);
        af[mf] = *(const short8*)(Ab + row * 128 + (cbb ^ ((row & 7) << 4)));
      }
      short8 bfr[8];
#pragma unroll
      for (int cf = 0; cf < 8; ++cf) {
        const int row = cf * 16 + (lane & 15);
        bfr[cf] = *(const short8*)(Bb + row * 128 + (cbb ^ ((row & 7) << 4)));
      }
#pragma unroll
      for (int mf = 0; mf < 2; ++mf)
#pragma unroll
        for (int cf = 0; cf < 8; ++cf)
          acc[mf][cf] = __builtin_amdgcn_mfma_f32_16x16x32_bf16(af[mf], bfr[cf], acc[mf][cf], 0, 0, 0);
    }
  }

  const int lc = lane & 15;
  const int lr = (lane >> 4) << 2;
  const int gm0 = m0 + wid * 32;

  if constexpr (EPI == 0) {
#pragma unroll
    for (int mf = 0; mf < 2; ++mf)
#pragma unroll
      for (int cf = 0; cf < 4; ++cf) {
        const int col = bn * 64 + cf * 16 + lc;
        const float bz = bias[col];
        const float bg = bias[1024 + col];
#pragma unroll
        for (int r = 0; r < 4; ++r) {
          const int m = gm0 + mf * 16 + lr + r;
          const float z = acc[mf][cf][r] + bz;
          const float g = acc[mf][cf + 4][r] + bg;
          const float y = z / (1.f + __expf(-z)) * (1.f / (1.f + __expf(-g)));
          outB[(size_t)m * 1024 + col] = f2b(y);
        }
      }
  } else if constexpr (EPI == 1) {
#pragma unroll
    for (int mf = 0; mf < 2; ++mf)
#pragma unroll
      for (int cf = 0; cf < 8; ++cf) {
        const int col = bn * 128 + cf * 16 + lc;
        const float bv = bias[col];
#pragma unroll
        for (int r = 0; r < 4; ++r) {
          const int m = gm0 + mf * 16 + lr + r;
          const float v = acc[mf][cf][r] + bv + res[(size_t)m * 512 + col];
          outB[(size_t)m * 1024 + coloff + col] = f2b(v);
        }
      }
  } else if constexpr (EPI == 2) {
#pragma unroll
    for (int mf = 0; mf < 2; ++mf)
#pragma unroll
      for (int cf = 0; cf < 8; ++cf) {
        const int col = bn * 128 + cf * 16 + lc;
        const float bv = bias[col];
#pragma unroll
        for (int r = 0; r < 4; ++r) {
          const int m = gm0 + mf * 16 + lr + r;
          outF[(size_t)m * 512 + col] = acc[mf][cf][r] + bv + res[(size_t)m * 512 + col];
        }
      }
  } else if constexpr (EPI == 3) {
#pragma unroll
    for (int mf = 0; mf < 2; ++mf)
#pragma unroll
      for (int cf = 0; cf < 8; ++cf) {
        const int col = bn * 128 + cf * 16 + lc;
        const float bv = bias[col];
#pragma unroll
        for (int r = 0; r < 4; ++r) {
          const int m = gm0 + mf * 16 + lr + r;
          const float v = acc[mf][cf][r] + bv;
          outB[(size_t)m * 2048 + col] = f2b(0.5f * v * (1.f + erff(v * 0.70710678f)));
        }
      }
  } else {
#pragma unroll
    for (int mf = 0; mf < 2; ++mf)
#pragma unroll
      for (int cf = 0; cf < 8; ++cf) {
        const int col = bn * 128 + cf * 16 + lc;
        const float bv = bias[col];
#pragma unroll
        for (int r = 0; r < 4; ++r) {
          const int m = gm0 + mf * 16 + lr + r;
          outF[(size_t)m * 512 + col] =
              (acc[mf][cf][r] + bv + res[(size_t)m * 512 + col]) * kmask[m];
        }
      }
  }
}

// LN(s) with two param sets -> two bf16 outputs. One wave per row of 512.
__global__ void dual_ln_512(const float* __restrict__ x,
                            const float* __restrict__ w1, const float* __restrict__ b1,
                            const float* __restrict__ w2, const float* __restrict__ b2,
                            u16* __restrict__ o1, u16* __restrict__ o2) {
  const int row = blockIdx.x * 4 + (threadIdx.x >> 6);
  const int lane = threadIdx.x & 63;
  const float* xr = x + (size_t)row * 512;
  float v[8];
  *(float4*)&v[0] = *(const float4*)(xr + lane * 4);
  *(float4*)&v[4] = *(const float4*)(xr + 256 + lane * 4);
  float s = 0.f, q = 0.f;
#pragma unroll
  for (int j = 0; j < 8; ++j) { s += v[j]; q += v[j] * v[j]; }
  s = wred(s); q = wred(q);
  const float mean = s * (1.f / 512.f);
  const float rstd = rsqrtf(q * (1.f / 512.f) - mean * mean + 1e-5f);
  float wa[8], ba[8], wb[8], bb[8];
  *(float4*)&wa[0] = *(const float4*)(w1 + lane * 4);
  *(float4*)&wa[4] = *(const float4*)(w1 + 256 + lane * 4);
  *(float4*)&ba[0] = *(const float4*)(b1 + lane * 4);
  *(float4*)&ba[4] = *(const float4*)(b1 + 256 + lane * 4);
  *(float4*)&wb[0] = *(const float4*)(w2 + lane * 4);
  *(float4*)&wb[4] = *(const float4*)(w2 + 256 + lane * 4);
  *(float4*)&bb[0] = *(const float4*)(b2 + lane * 4);
  *(float4*)&bb[4] = *(const float4*)(b2 + 256 + lane * 4);
  u16 oa[8], ob[8];
#pragma unroll
  for (int j = 0; j < 8; ++j) {
    const float nv = (v[j] - mean) * rstd;
    oa[j] = f2b(nv * wa[j] + ba[j]);
    ob[j] = f2b(nv * wb[j] + bb[j]);
  }
  *(u16x4*)(o1 + (size_t)row * 512 + lane * 4) = *(u16x4*)&oa[0];
  *(u16x4*)(o1 + (size_t)row * 512 + 256 + lane * 4) = *(u16x4*)&oa[4];
  *(u16x4*)(o2 + (size_t)row * 512 + lane * 4) = *(u16x4*)&ob[0];
  *(u16x4*)(o2 + (size_t)row * 512 + 256 + lane * 4) = *(u16x4*)&ob[4];
}

// in-place LN over rows of 1024 (bf16 storage, fp32 stats)
__global__ void ln_bf16_1024(u16* __restrict__ y, const float* __restrict__ w,
                             const float* __restrict__ b) {
  const int row = blockIdx.x * 4 + (threadIdx.x >> 6);
  const int lane = threadIdx.x & 63;
  u16* yr = y + (size_t)row * 1024;
  const short8 a0 = *(const short8*)(yr + lane * 8);
  const short8 a1 = *(const short8*)(yr + 512 + lane * 8);
  float v[16];
#pragma unroll
  for (int j = 0; j < 8; ++j) { v[j] = b2f((u16)a0[j]); v[8 + j] = b2f((u16)a1[j]); }
  float s = 0.f, q = 0.f;
#pragma unroll
  for (int j = 0; j < 16; ++j) { s += v[j]; q += v[j] * v[j]; }
  s = wred(s); q = wred(q);
  const float mean = s * (1.f / 1024.f);
  const float rstd = rsqrtf(q * (1.f / 1024.f) - mean * mean + 1e-5f);
  float wv[16], bv[16];
  *(float4*)&wv[0] = *(const float4*)(w + lane * 8);
  *(float4*)&wv[4] = *(const float4*)(w + lane * 8 + 4);
  *(float4*)&wv[8] = *(const float4*)(w + 512 + lane * 8);
  *(float4*)&wv[12] = *(const float4*)(w + 512 + lane * 8 + 4);
  *(float4*)&bv[0] = *(const float4*)(b + lane * 8);
  *(float4*)&bv[4] = *(const float4*)(b + lane * 8 + 4);
  *(float4*)&bv[8] = *(const float4*)(b + 512 + lane * 8);
  *(float4*)&bv[12] = *(const float4*)(b + 512 + lane * 8 + 4);
  u16 o[16];
#pragma unroll
  for (int j = 0; j < 16; ++j) o[j] = f2b((v[j] - mean) * rstd * wv[j] + bv[j]);
  *(short8*)(yr + lane * 8) = *(short8*)&o[0];
  *(short8*)(yr + 512 + lane * 8) = *(short8*)&o[8];
}

// t = LN(t_pre; nrm) written in place (fp32), h = LN(t; ffn_ln) -> bf16
__global__ void dual_ln_t(float* __restrict__ t,
                          const float* __restrict__ nw, const float* __restrict__ nb,
                          const float* __restrict__ fw, const float* __restrict__ fb,
                          u16* __restrict__ h) {
  const int row = blockIdx.x * 4 + (threadIdx.x >> 6);
  const int lane = threadIdx.x & 63;
  float* tr = t + (size_t)row * 512;
  float v[8];
  *(float4*)&v[0] = *(const float4*)(tr + lane * 4);
  *(float4*)&v[4] = *(const float4*)(tr + 256 + lane * 4);
  float s = 0.f, q = 0.f;
#pragma unroll
  for (int j = 0; j < 8; ++j) { s += v[j]; q += v[j] * v[j]; }
  s = wred(s); q = wred(q);
  const float mean = s * (1.f / 512.f);
  const float rstd = rsqrtf(q * (1.f / 512.f) - mean * mean + 1e-5f);
  float nwv[8], nbv[8], fwv[8], fbv[8];
  *(float4*)&nwv[0] = *(const float4*)(nw + lane * 4);
  *(float4*)&nwv[4] = *(const float4*)(nw + 256 + lane * 4);
  *(float4*)&nbv[0] = *(const float4*)(nb + lane * 4);
  *(float4*)&nbv[4] = *(const float4*)(nb + 256 + lane * 4);
  *(float4*)&fwv[0] = *(const float4*)(fw + lane * 4);
  *(float4*)&fwv[4] = *(const float4*)(fw + 256 + lane * 4);
  *(float4*)&fbv[0] = *(const float4*)(fb + lane * 4);
  *(float4*)&fbv[4] = *(const float4*)(fb + 256 + lane * 4);
  float tv[8];
#pragma unroll
  for (int j = 0; j < 8; ++j) tv[j] = (v[j] - mean) * rstd * nwv[j] + nbv[j];
  *(float4*)(tr + lane * 4) = *(float4*)&tv[0];
  *(float4*)(tr + 256 + lane * 4) = *(float4*)&tv[4];
  float s2 = 0.f, q2 = 0.f;
#pragma unroll
  for (int j = 0; j < 8; ++j) { s2 += tv[j]; q2 += tv[j] * tv[j]; }
  s2 = wred(s2); q2 = wred(q2);
  const float mean2 = s2 * (1.f / 512.f);
  const float rstd2 = rsqrtf(q2 * (1.f / 512.f) - mean2 * mean2 + 1e-5f);
  u16 o[8];
#pragma unroll
  for (int j = 0; j < 8; ++j) o[j] = f2b((tv[j] - mean2) * rstd2 * fwv[j] + fbv[j]);
  *(u16x4*)(h + (size_t)row * 512 + lane * 4) = *(u16x4*)&o[0];
  *(u16x4*)(h + (size_t)row * 512 + 256 + lane * 4) = *(u16x4*)&o[4];
}

__global__ void cvt_f32_bf16(const float* __restrict__ s, u16* __restrict__ d, const int n) {
  const int i = (blockIdx.x * 256 + threadIdx.x) * 4;
  if (i >= n) return;
  const float4 v = *(const float4*)(s + i);
  u16x4 o = {f2b(v.x), f2b(v.y), f2b(v.z), f2b(v.w)};
  *(u16x4*)(d + i) = o;
}

extern "C" void kernel_launch(void* const* d_in, const int* in_sizes, int n_in,
                              void* d_out, int out_size, void* d_ws, size_t ws_size,
                              hipStream_t stream) {
  (void)in_sizes; (void)n_in; (void)out_size; (void)ws_size;
  constexpr int M = 16 * 2048;

  const float* s0        = (const float*)d_in[0];
  const float* km        = (const float*)d_in[1];
  const float* fwd_ln_w  = (const float*)d_in[2];
  const float* fwd_ln_b  = (const float*)d_in[3];
  const float* fwd_pin_w = (const float*)d_in[4];
  const float* fwd_pin_b = (const float*)d_in[5];
  const float* fwd_pout_w= (const float*)d_in[6];
  const float* fwd_pout_b= (const float*)d_in[7];
  const float* fwd_iln_w = (const float*)d_in[8];
  const float* fwd_iln_b = (const float*)d_in[9];
  const float* bwd_ln_w  = (const float*)d_in[10];
  const float* bwd_ln_b  = (const float*)d_in[11];
  const float* bwd_pin_w = (const float*)d_in[12];
  const float* bwd_pin_b = (const float*)d_in[13];
  const float* bwd_pout_w= (const float*)d_in[14];
  const float* bwd_pout_b= (const float*)d_in[15];
  const float* bwd_iln_w = (const float*)d_in[16];
  const float* bwd_iln_b = (const float*)d_in[17];
  const float* mrg_w     = (const float*)d_in[18];
  const float* mrg_b     = (const float*)d_in[19];
  const float* nrm_w     = (const float*)d_in[20];
  const float* nrm_b     = (const float*)d_in[21];
  const float* ffn_ln_w  = (const float*)d_in[22];
  const float* ffn_ln_b  = (const float*)d_in[23];
  const float* ffn_w1    = (const float*)d_in[24];
  const float* ffn_b1    = (const float*)d_in[25];
  const float* ffn_w2    = (const float*)d_in[26];
  const float* ffn_b2    = (const float*)d_in[27];

  // Workspace: 226 MB total (fits conservative ws_size).
  //   T   f32 [M,512]   64MB  (live: merge-GEMM .. FFN2)
  //   Xb  bf16 [M,512]  aliases T[0:32MB] (dead before T's first write)
  //   Xf  bf16 [M,512]  32MB
  //   YH  bf16 128MB: Y=[0:64MB), FB=[64:128MB), H1=whole (disjoint lifetimes)
  //   Wss bf16 2MB: per-GEMM weight conversion scratch (stream-serialized reuse)
  char* p = (char*)d_ws;
  auto alloc = [&](size_t bytes) { char* r = p; p += bytes; return r; };
  float* T  = (float*)alloc((size_t)M * 512 * 4);
  u16* Xf   = (u16*)alloc((size_t)M * 512 * 2);
  u16* YH   = (u16*)alloc((size_t)M * 2048 * 2);
  u16* Wss  = (u16*)alloc((size_t)2048 * 512 * 2);
  u16* Xb = (u16*)T;
  u16* Y  = YH;
  u16* FB = YH + (size_t)M * 1024;
  u16* H1 = YH;

  for (int L = 0; L < 2; ++L) {
    const float* sin = L ? (const float*)d_out : s0;  // layer-0 output parked in d_out
    float* sout = (float*)d_out;
    dual_ln_512<<<M / 4, 256, 0, stream>>>(sin, fwd_ln_w + L * 512, fwd_ln_b + L * 512,
                                           bwd_ln_w + L * 512, bwd_ln_b + L * 512, Xf, Xb);
    // fwd SSM branch
    cvt_f32_bf16<<<1024, 256, 0, stream>>>(fwd_pin_w + (size_t)L * 2048 * 512, Wss, 2048 * 512);
    gemm_tn<0><<<dim3(16, M / 128), 256, 0, stream>>>(Xf, Wss, 512,
        fwd_pin_b + L * 2048, nullptr, nullptr, nullptr, Y, 0);
    ln_bf16_1024<<<M / 4, 256, 0, stream>>>(Y, fwd_iln_w + L * 1024, fwd_iln_b + L * 1024);
    cvt_f32_bf16<<<512, 256, 0, stream>>>(fwd_pout_w + (size_t)L * 512 * 1024, Wss, 512 * 1024);
    gemm_tn<1><<<dim3(4, M / 128), 256, 0, stream>>>(Y, Wss, 1024,
        fwd_pout_b + L * 512, sin, nullptr, nullptr, FB, 0);
    // bwd SSM branch (flips cancel: position-wise)
    cvt_f32_bf16<<<1024, 256, 0, stream>>>(bwd_pin_w + (size_t)L * 2048 * 512, Wss, 2048 * 512);
    gemm_tn<0><<<dim3(16, M / 128), 256, 0, stream>>>(Xb, Wss, 512,
        bwd_pin_b + L * 2048, nullptr, nullptr, nullptr, Y, 0);
    ln_bf16_1024<<<M / 4, 256, 0, stream>>>(Y, bwd_iln_w + L * 1024, bwd_iln_b + L * 1024);
    cvt_f32_bf16<<<512, 256, 0, stream>>>(bwd_pout_w + (size_t)L * 512 * 1024, Wss, 512 * 1024);
    gemm_tn<1><<<dim3(4, M / 128), 256, 0, stream>>>(Y, Wss, 1024,
        bwd_pout_b + L * 512, sin, nullptr, nullptr, FB, 512);
    // merge + residual -> t_pre (fp32)
    cvt_f32_bf16<<<512, 256, 0, stream>>>(mrg_w + (size_t)L * 512 * 1024, Wss, 512 * 1024);
    gemm_tn<2><<<dim3(4, M / 128), 256, 0, stream>>>(FB, Wss, 1024,
        mrg_b + L * 512, sin, nullptr, T, nullptr, 0);
    // t = LN(t_pre; nrm) in place; h = LN(t; ffn_ln) -> Xf (bf16)
    dual_ln_t<<<M / 4, 256, 0, stream>>>(T, nrm_w + L * 512, nrm_b + L * 512,
                                         ffn_ln_w + L * 512, ffn_ln_b + L * 512, Xf);
    // FFN
    cvt_f32_bf16<<<1024, 256, 0, stream>>>(ffn_w1 + (size_t)L * 2048 * 512, Wss, 2048 * 512);
    gemm_tn<3><<<dim3(16, M / 128), 256, 0, stream>>>(Xf, Wss, 512,
        ffn_b1 + L * 2048, nullptr, nullptr, nullptr, H1, 0);
    cvt_f32_bf16<<<1024, 256, 0, stream>>>(ffn_w2 + (size_t)L * 512 * 2048, Wss, 512 * 2048);
    gemm_tn<4><<<dim3(4, M / 128), 256, 0, stream>>>(H1, Wss, 2048,
        ffn_b2 + L * 512, T, km, sout, nullptr, 0);
  }
}

// Round 5
// 1555.488 us; speedup vs baseline: 1.0296x; 1.0296x over previous
//
#include <hip/hip_runtime.h>
#include <math.h>

typedef unsigned short u16;
typedef __attribute__((ext_vector_type(8))) short short8;
typedef __attribute__((ext_vector_type(4))) float f32x4;
typedef __attribute__((ext_vector_type(4))) unsigned short u16x4;

#define DEV static __device__ __forceinline__

DEV float b2f(u16 u) { unsigned v = ((unsigned)u) << 16; float f; __builtin_memcpy(&f, &v, 4); return f; }
DEV u16 f2b(float f) {
  unsigned u; __builtin_memcpy(&u, &f, 4);
  u += 0x7fffu + ((u >> 16) & 1u);
  return (u16)(u >> 16);
}

DEV float wred(float v) {
#pragma unroll
  for (int m = 1; m < 64; m <<= 1) v += __shfl_xor(v, m, 64);
  return v;
}

DEV void gld_lds16(const u16* src, u16* lds_dst) {
  __builtin_amdgcn_global_load_lds(
      (const __attribute__((address_space(1))) void*)src,
      (__attribute__((address_space(3))) void*)lds_dst, 16, 0, 0);
}

// ---------------------------------------------------------------------------
// Big-tile GEMM: C = A[M,K](lda) @ W[N,K]^T, BM=128 BN=256 BK=64, 8 waves
// (2 M x 4 N), per-wave 64x64 output. 3-stage LDS pipeline (144KB): loads for
// tile kt+2 issued during tile kt; per-wave s_waitcnt vmcnt(6) BEFORE the raw
// s_barrier => tile kt+1 landed for every wave once all pass the barrier;
// steady state never drains vmcnt to 0 (T3+T4). LDS dest is the wave-uniform
// base (lane x 16B placement is the hardware's); global src per-lane carries
// the XOR swizzle; same XOR applied on ds_read (R3 PMC: 0 bank conflicts).
// EPI 0: GLU fused. Virtual B row v (0..255): s=v>>6, t=v&63;
//        t<32 -> Wz row bn*128+s*32+t ; t>=32 -> Wg row 1024+bn*128+s*32+t-32.
//        Wave wc frags nf{0,1}=z cols, nf{2,3}=matching g cols ->
//        y = silu(z+bz)*sigmoid(g+bg) -> bf16 outB[M,1024].
// EPI 1: acc+bias+res -> bf16 outB[M,1024] at coloff
// EPI 2: acc+bias+res -> f32 outF[M,512]
// EPI 3: gelu(acc+bias) -> bf16 outB[M,2048]
// EPI 4: (acc+bias+res)*km -> f32 outF[M,512]
// ---------------------------------------------------------------------------
template <int EPI>
__global__ __launch_bounds__(512, 1) void gemm_big(
    const u16* __restrict__ A, const int lda, const u16* __restrict__ W, const int K,
    const float* __restrict__ bias, const float* __restrict__ res,
    const float* __restrict__ kmask, float* __restrict__ outF,
    u16* __restrict__ outB, const int coloff) {
  __shared__ u16 sh[3 * 24576];  // per stage: A 128x64 (16KB) + B 256x64 (32KB)
  const int tid = threadIdx.x;
  const int wid = tid >> 6;
  const int lane = tid & 63;
  const int wr = wid >> 2;   // 0..1 (M half)
  const int wc = wid & 3;    // 0..3 (N quarter)
  const int bn = blockIdx.x;
  const int m0 = blockIdx.y << 7;

  f32x4 acc[4][4];
#pragma unroll
  for (int a = 0; a < 4; ++a)
#pragma unroll
    for (int b = 0; b < 4; ++b) acc[a][b] = f32x4{0.f, 0.f, 0.f, 0.f};

  const int KT = K >> 6;

  auto issue = [&](int kt) {
    const int st = kt % 3;
    const int k0 = kt << 6;
    // A tile: 16KB = 2 chunks of (512 thr x 16B); wave-uniform LDS base.
#pragma unroll
    for (int i = 0; i < 2; ++i) {
      const int jb = wid * 1024 + i * 8192;        // wave base byte in A tile
      const int j = jb + lane * 16;                // this lane's byte
      const int row = j >> 7, c = (j >> 4) & 7;
      const u16* src = A + (size_t)(m0 + row) * lda + k0 + ((c ^ (row & 7)) << 3);
      gld_lds16(src, &sh[st * 24576 + (jb >> 1)]);
    }
    // B tile: 32KB = 4 chunks
#pragma unroll
    for (int i = 0; i < 4; ++i) {
      const int jb = wid * 1024 + i * 8192;
      const int j = jb + lane * 16;
      const int row = j >> 7, c = (j >> 4) & 7;
      int wrow;
      if constexpr (EPI == 0) {
        const int s = row >> 6, t = row & 63;
        wrow = (t < 32) ? (bn * 128 + s * 32 + t) : (1024 + bn * 128 + s * 32 + (t - 32));
      } else {
        wrow = bn * 256 + row;
      }
      const u16* src = W + (size_t)wrow * K + k0 + ((c ^ (row & 7)) << 3);
      gld_lds16(src, &sh[st * 24576 + 8192 + (jb >> 1)]);
    }
  };

  issue(0);
  issue(1);
  asm volatile("s_waitcnt vmcnt(6)" ::: "memory");  // tile0 landed; tile1 in flight
  __builtin_amdgcn_s_barrier();
  __builtin_amdgcn_sched_barrier(0);

  for (int kt = 0; kt < KT; ++kt) {
    const char* Ab = (const char*)&sh[(kt % 3) * 24576];
    const char* Bb = Ab + 16384;
    if (kt + 2 < KT) issue(kt + 2);  // targets buf[(kt-1)%3]: readers passed barrier
#pragma unroll
    for (int kk = 0; kk < 2; ++kk) {
      const int cbb = kk * 64 + ((lane >> 4) << 4);
      short8 af[4], bf[4];
#pragma unroll
      for (int mf = 0; mf < 4; ++mf) {
        const int row = wr * 64 + mf * 16 + (lane & 15);
        af[mf] = *(const short8*)(Ab + row * 128 + (cbb ^ ((row & 7) << 4)));
      }
#pragma unroll
      for (int nf = 0; nf < 4; ++nf) {
        const int row = wc * 64 + nf * 16 + (lane & 15);
        bf[nf] = *(const short8*)(Bb + row * 128 + (cbb ^ ((row & 7) << 4)));
      }
      __builtin_amdgcn_s_setprio(1);
#pragma unroll
      for (int mf = 0; mf < 4; ++mf)
#pragma unroll
        for (int nf = 0; nf < 4; ++nf)
          acc[mf][nf] = __builtin_amdgcn_mfma_f32_16x16x32_bf16(af[mf], bf[nf], acc[mf][nf], 0, 0, 0);
      __builtin_amdgcn_s_setprio(0);
    }
    if (kt + 1 < KT) {
      if (kt + 2 < KT) asm volatile("s_waitcnt vmcnt(6)" ::: "memory");  // kt+1 done, kt+2 in flight
      else             asm volatile("s_waitcnt vmcnt(0)" ::: "memory");  // last prefetch drain
      __builtin_amdgcn_s_barrier();
      __builtin_amdgcn_sched_barrier(0);
    }
  }

  const int lc = lane & 15;
  const int lr = (lane >> 4) << 2;
  const int gm0 = m0 + wr * 64;

  if constexpr (EPI == 0) {
#pragma unroll
    for (int mf = 0; mf < 4; ++mf)
#pragma unroll
      for (int nf = 0; nf < 2; ++nf) {
        const int col = bn * 128 + wc * 32 + nf * 16 + lc;
        const float bz = bias[col];
        const float bg = bias[1024 + col];
#pragma unroll
        for (int r = 0; r < 4; ++r) {
          const int m = gm0 + mf * 16 + lr + r;
          const float z = acc[mf][nf][r] + bz;
          const float g = acc[mf][nf + 2][r] + bg;
          const float y = z / (1.f + __expf(-z)) * (1.f / (1.f + __expf(-g)));
          outB[(size_t)m * 1024 + col] = f2b(y);
        }
      }
  } else if constexpr (EPI == 1) {
#pragma unroll
    for (int mf = 0; mf < 4; ++mf)
#pragma unroll
      for (int nf = 0; nf < 4; ++nf) {
        const int col = bn * 256 + wc * 64 + nf * 16 + lc;
        const float bv = bias[col];
#pragma unroll
        for (int r = 0; r < 4; ++r) {
          const int m = gm0 + mf * 16 + lr + r;
          const float v = acc[mf][nf][r] + bv + res[(size_t)m * 512 + col];
          outB[(size_t)m * 1024 + coloff + col] = f2b(v);
        }
      }
  } else if constexpr (EPI == 2) {
#pragma unroll
    for (int mf = 0; mf < 4; ++mf)
#pragma unroll
      for (int nf = 0; nf < 4; ++nf) {
        const int col = bn * 256 + wc * 64 + nf * 16 + lc;
        const float bv = bias[col];
#pragma unroll
        for (int r = 0; r < 4; ++r) {
          const int m = gm0 + mf * 16 + lr + r;
          outF[(size_t)m * 512 + col] = acc[mf][nf][r] + bv + res[(size_t)m * 512 + col];
        }
      }
  } else if constexpr (EPI == 3) {
#pragma unroll
    for (int mf = 0; mf < 4; ++mf)
#pragma unroll
      for (int nf = 0; nf < 4; ++nf) {
        const int col = bn * 256 + wc * 64 + nf * 16 + lc;
        const float bv = bias[col];
#pragma unroll
        for (int r = 0; r < 4; ++r) {
          const int m = gm0 + mf * 16 + lr + r;
          const float v = acc[mf][nf][r] + bv;
          outB[(size_t)m * 2048 + col] = f2b(0.5f * v * (1.f + erff(v * 0.70710678f)));
        }
      }
  } else {
#pragma unroll
    for (int mf = 0; mf < 4; ++mf)
#pragma unroll
      for (int nf = 0; nf < 4; ++nf) {
        const int col = bn * 256 + wc * 64 + nf * 16 + lc;
        const float bv = bias[col];
#pragma unroll
        for (int r = 0; r < 4; ++r) {
          const int m = gm0 + mf * 16 + lr + r;
          outF[(size_t)m * 512 + col] =
              (acc[mf][nf][r] + bv + res[(size_t)m * 512 + col]) * kmask[m];
        }
      }
  }
}

// LN(s) with two param sets -> two bf16 outputs. One wave per row of 512.
__global__ void dual_ln_512(const float* __restrict__ x,
                            const float* __restrict__ w1, const float* __restrict__ b1,
                            const float* __restrict__ w2, const float* __restrict__ b2,
                            u16* __restrict__ o1, u16* __restrict__ o2) {
  const int row = blockIdx.x * 4 + (threadIdx.x >> 6);
  const int lane = threadIdx.x & 63;
  const float* xr = x + (size_t)row * 512;
  float v[8];
  *(float4*)&v[0] = *(const float4*)(xr + lane * 4);
  *(float4*)&v[4] = *(const float4*)(xr + 256 + lane * 4);
  float s = 0.f, q = 0.f;
#pragma unroll
  for (int j = 0; j < 8; ++j) { s += v[j]; q += v[j] * v[j]; }
  s = wred(s); q = wred(q);
  const float mean = s * (1.f / 512.f);
  const float rstd = rsqrtf(q * (1.f / 512.f) - mean * mean + 1e-5f);
  float wa[8], ba[8], wb[8], bb[8];
  *(float4*)&wa[0] = *(const float4*)(w1 + lane * 4);
  *(float4*)&wa[4] = *(const float4*)(w1 + 256 + lane * 4);
  *(float4*)&ba[0] = *(const float4*)(b1 + lane * 4);
  *(float4*)&ba[4] = *(const float4*)(b1 + 256 + lane * 4);
  *(float4*)&wb[0] = *(const float4*)(w2 + lane * 4);
  *(float4*)&wb[4] = *(const float4*)(w2 + 256 + lane * 4);
  *(float4*)&bb[0] = *(const float4*)(b2 + lane * 4);
  *(float4*)&bb[4] = *(const float4*)(b2 + 256 + lane * 4);
  u16 oa[8], ob[8];
#pragma unroll
  for (int j = 0; j < 8; ++j) {
    const float nv = (v[j] - mean) * rstd;
    oa[j] = f2b(nv * wa[j] + ba[j]);
    ob[j] = f2b(nv * wb[j] + bb[j]);
  }
  *(u16x4*)(o1 + (size_t)row * 512 + lane * 4) = *(u16x4*)&oa[0];
  *(u16x4*)(o1 + (size_t)row * 512 + 256 + lane * 4) = *(u16x4*)&oa[4];
  *(u16x4*)(o2 + (size_t)row * 512 + lane * 4) = *(u16x4*)&ob[0];
  *(u16x4*)(o2 + (size_t)row * 512 + 256 + lane * 4) = *(u16x4*)&ob[4];
}

// in-place LN over rows of 1024 (bf16 storage, fp32 stats)
__global__ void ln_bf16_1024(u16* __restrict__ y, const float* __restrict__ w,
                             const float* __restrict__ b) {
  const int row = blockIdx.x * 4 + (threadIdx.x >> 6);
  const int lane = threadIdx.x & 63;
  u16* yr = y + (size_t)row * 1024;
  const short8 a0 = *(const short8*)(yr + lane * 8);
  const short8 a1 = *(const short8*)(yr + 512 + lane * 8);
  float v[16];
#pragma unroll
  for (int j = 0; j < 8; ++j) { v[j] = b2f((u16)a0[j]); v[8 + j] = b2f((u16)a1[j]); }
  float s = 0.f, q = 0.f;
#pragma unroll
  for (int j = 0; j < 16; ++j) { s += v[j]; q += v[j] * v[j]; }
  s = wred(s); q = wred(q);
  const float mean = s * (1.f / 1024.f);
  const float rstd = rsqrtf(q * (1.f / 1024.f) - mean * mean + 1e-5f);
  float wv[16], bv[16];
  *(float4*)&wv[0] = *(const float4*)(w + lane * 8);
  *(float4*)&wv[4] = *(const float4*)(w + lane * 8 + 4);
  *(float4*)&wv[8] = *(const float4*)(w + 512 + lane * 8);
  *(float4*)&wv[12] = *(const float4*)(w + 512 + lane * 8 + 4);
  *(float4*)&bv[0] = *(const float4*)(b + lane * 8);
  *(float4*)&bv[4] = *(const float4*)(b + lane * 8 + 4);
  *(float4*)&bv[8] = *(const float4*)(b + 512 + lane * 8);
  *(float4*)&bv[12] = *(const float4*)(b + 512 + lane * 8 + 4);
  u16 o[16];
#pragma unroll
  for (int j = 0; j < 16; ++j) o[j] = f2b((v[j] - mean) * rstd * wv[j] + bv[j]);
  *(short8*)(yr + lane * 8) = *(short8*)&o[0];
  *(short8*)(yr + 512 + lane * 8) = *(short8*)&o[8];
}

// t = LN(t_pre; nrm) written in place (fp32), h = LN(t; ffn_ln) -> bf16
__global__ void dual_ln_t(float* __restrict__ t,
                          const float* __restrict__ nw, const float* __restrict__ nb,
                          const float* __restrict__ fw, const float* __restrict__ fb,
                          u16* __restrict__ h) {
  const int row = blockIdx.x * 4 + (threadIdx.x >> 6);
  const int lane = threadIdx.x & 63;
  float* tr = t + (size_t)row * 512;
  float v[8];
  *(float4*)&v[0] = *(const float4*)(tr + lane * 4);
  *(float4*)&v[4] = *(const float4*)(tr + 256 + lane * 4);
  float s = 0.f, q = 0.f;
#pragma unroll
  for (int j = 0; j < 8; ++j) { s += v[j]; q += v[j] * v[j]; }
  s = wred(s); q = wred(q);
  const float mean = s * (1.f / 512.f);
  const float rstd = rsqrtf(q * (1.f / 512.f) - mean * mean + 1e-5f);
  float nwv[8], nbv[8], fwv[8], fbv[8];
  *(float4*)&nwv[0] = *(const float4*)(nw + lane * 4);
  *(float4*)&nwv[4] = *(const float4*)(nw + 256 + lane * 4);
  *(float4*)&nbv[0] = *(const float4*)(nb + lane * 4);
  *(float4*)&nbv[4] = *(const float4*)(nb + 256 + lane * 4);
  *(float4*)&fwv[0] = *(const float4*)(fw + lane * 4);
  *(float4*)&fwv[4] = *(const float4*)(fw + 256 + lane * 4);
  *(float4*)&fbv[0] = *(const float4*)(fb + lane * 4);
  *(float4*)&fbv[4] = *(const float4*)(fb + 256 + lane * 4);
  float tv[8];
#pragma unroll
  for (int j = 0; j < 8; ++j) tv[j] = (v[j] - mean) * rstd * nwv[j] + nbv[j];
  *(float4*)(tr + lane * 4) = *(float4*)&tv[0];
  *(float4*)(tr + 256 + lane * 4) = *(float4*)&tv[4];
  float s2 = 0.f, q2 = 0.f;
#pragma unroll
  for (int j = 0; j < 8; ++j) { s2 += tv[j]; q2 += tv[j] * tv[j]; }
  s2 = wred(s2); q2 = wred(q2);
  const float mean2 = s2 * (1.f / 512.f);
  const float rstd2 = rsqrtf(q2 * (1.f / 512.f) - mean2 * mean2 + 1e-5f);
  u16 o[8];
#pragma unroll
  for (int j = 0; j < 8; ++j) o[j] = f2b((tv[j] - mean2) * rstd2 * fwv[j] + fbv[j]);
  *(u16x4*)(h + (size_t)row * 512 + lane * 4) = *(u16x4*)&o[0];
  *(u16x4*)(h + (size_t)row * 512 + 256 + lane * 4) = *(u16x4*)&o[4];
}

__global__ void cvt_f32_bf16(const float* __restrict__ s, u16* __restrict__ d, const int n) {
  const int i = (blockIdx.x * 256 + threadIdx.x) * 4;
  if (i >= n) return;
  const float4 v = *(const float4*)(s + i);
  u16x4 o = {f2b(v.x), f2b(v.y), f2b(v.z), f2b(v.w)};
  *(u16x4*)(d + i) = o;
}

extern "C" void kernel_launch(void* const* d_in, const int* in_sizes, int n_in,
                              void* d_out, int out_size, void* d_ws, size_t ws_size,
                              hipStream_t stream) {
  (void)in_sizes; (void)n_in; (void)out_size; (void)ws_size;
  constexpr int M = 16 * 2048;

  const float* s0        = (const float*)d_in[0];
  const float* km        = (const float*)d_in[1];
  const float* fwd_ln_w  = (const float*)d_in[2];
  const float* fwd_ln_b  = (const float*)d_in[3];
  const float* fwd_pin_w = (const float*)d_in[4];
  const float* fwd_pin_b = (const float*)d_in[5];
  const float* fwd_pout_w= (const float*)d_in[6];
  const float* fwd_pout_b= (const float*)d_in[7];
  const float* fwd_iln_w = (const float*)d_in[8];
  const float* fwd_iln_b = (const float*)d_in[9];
  const float* bwd_ln_w  = (const float*)d_in[10];
  const float* bwd_ln_b  = (const float*)d_in[11];
  const float* bwd_pin_w = (const float*)d_in[12];
  const float* bwd_pin_b = (const float*)d_in[13];
  const float* bwd_pout_w= (const float*)d_in[14];
  const float* bwd_pout_b= (const float*)d_in[15];
  const float* bwd_iln_w = (const float*)d_in[16];
  const float* bwd_iln_b = (const float*)d_in[17];
  const float* mrg_w     = (const float*)d_in[18];
  const float* mrg_b     = (const float*)d_in[19];
  const float* nrm_w     = (const float*)d_in[20];
  const float* nrm_b     = (const float*)d_in[21];
  const float* ffn_ln_w  = (const float*)d_in[22];
  const float* ffn_ln_b  = (const float*)d_in[23];
  const float* ffn_w1    = (const float*)d_in[24];
  const float* ffn_b1    = (const float*)d_in[25];
  const float* ffn_w2    = (const float*)d_in[26];
  const float* ffn_b2    = (const float*)d_in[27];

  // Workspace: 226 MiB (proven safe in R3; 290 MiB aborted => ws ~256 MiB).
  //   T   f32 [M,512]  64MiB (Xb bf16 aliases first 32MiB; dead before T's first write)
  //   Xf  bf16 [M,512] 32MiB
  //   ZH  bf16 [M,2048] 128MiB: Y=[0,64MiB) FB=[64,128MiB) H1=whole (disjoint lifetimes)
  //   Wss bf16 2MiB per-GEMM weight-conversion scratch
  char* p = (char*)d_ws;
  auto alloc = [&](size_t bytes) { char* r = p; p += bytes; return r; };
  float* T  = (float*)alloc((size_t)M * 512 * 4);
  u16* Xf   = (u16*)alloc((size_t)M * 512 * 2);
  u16* ZH   = (u16*)alloc((size_t)M * 2048 * 2);
  u16* Wss  = (u16*)alloc((size_t)2048 * 512 * 2);
  u16* Xb = (u16*)T;
  u16* Y  = ZH;
  u16* FB = ZH + (size_t)M * 1024;
  u16* H1 = ZH;

  const dim3 blk(512);
  for (int L = 0; L < 2; ++L) {
    const float* sin = L ? (const float*)d_out : s0;  // layer-0 output parked in d_out
    float* sout = (float*)d_out;
    dual_ln_512<<<M / 4, 256, 0, stream>>>(sin, fwd_ln_w + L * 512, fwd_ln_b + L * 512,
                                           bwd_ln_w + L * 512, bwd_ln_b + L * 512, Xf, Xb);
    // fwd SSM branch
    cvt_f32_bf16<<<1024, 256, 0, stream>>>(fwd_pin_w + (size_t)L * 2048 * 512, Wss, 2048 * 512);
    gemm_big<0><<<dim3(8, M / 128), blk, 0, stream>>>(Xf, 512, Wss, 512,
        fwd_pin_b + L * 2048, nullptr, nullptr, nullptr, Y, 0);
    ln_bf16_1024<<<M / 4, 256, 0, stream>>>(Y, fwd_iln_w + L * 1024, fwd_iln_b + L * 1024);
    cvt_f32_bf16<<<512, 256, 0, stream>>>(fwd_pout_w + (size_t)L * 512 * 1024, Wss, 512 * 1024);
    gemm_big<1><<<dim3(2, M / 128), blk, 0, stream>>>(Y, 1024, Wss, 1024,
        fwd_pout_b + L * 512, sin, nullptr, nullptr, FB, 0);
    // bwd SSM branch (flips cancel: position-wise)
    cvt_f32_bf16<<<1024, 256, 0, stream>>>(bwd_pin_w + (size_t)L * 2048 * 512, Wss, 2048 * 512);
    gemm_big<0><<<dim3(8, M / 128), blk, 0, stream>>>(Xb, 512, Wss, 512,
        bwd_pin_b + L * 2048, nullptr, nullptr, nullptr, Y, 0);
    ln_bf16_1024<<<M / 4, 256, 0, stream>>>(Y, bwd_iln_w + L * 1024, bwd_iln_b + L * 1024);
    cvt_f32_bf16<<<512, 256, 0, stream>>>(bwd_pout_w + (size_t)L * 512 * 1024, Wss, 512 * 1024);
    gemm_big<1><<<dim3(2, M / 128), blk, 0, stream>>>(Y, 1024, Wss, 1024,
        bwd_pout_b + L * 512, sin, nullptr, nullptr, FB, 512);
    // merge + residual -> t_pre (fp32)
    cvt_f32_bf16<<<512, 256, 0, stream>>>(mrg_w + (size_t)L * 512 * 1024, Wss, 512 * 1024);
    gemm_big<2><<<dim3(2, M / 128), blk, 0, stream>>>(FB, 1024, Wss, 1024,
        mrg_b + L * 512, sin, nullptr, T, nullptr, 0);
    // t = LN(t_pre; nrm) in place; h = LN(t; ffn_ln) -> Xf (bf16)
    dual_ln_t<<<M / 4, 256, 0, stream>>>(T, nrm_w + L * 512, nrm_b + L * 512,
                                         ffn_ln_w + L * 512, ffn_ln_b + L * 512, Xf);
    // FFN
    cvt_f32_bf16<<<1024, 256, 0, stream>>>(ffn_w1 + (size_t)L * 2048 * 512, Wss, 2048 * 512);
    gemm_big<3><<<dim3(8, M / 128), blk, 0, stream>>>(Xf, 512, Wss, 512,
        ffn_b1 + L * 2048, nullptr, nullptr, nullptr, H1, 0);
    cvt_f32_bf16<<<1024, 256, 0, stream>>>(ffn_w2 + (size_t)L * 512 * 2048, Wss, 512 * 2048);
    gemm_big<4><<<dim3(2, M / 128), blk, 0, stream>>>(H1, 2048, Wss, 2048,
        ffn_b2 + L * 512, T, km, sout, nullptr, 0);
  }
}